// Round 1
// baseline (769.000 us; speedup 1.0000x reference)
//
#include <hip/hip_runtime.h>

// Problem constants (match reference)
#define NN 500000          // nodes
#define FF 128             // feature dim
#define EE 4000000         // edges
#define BB 4               // graphs
#define GG 32              // voxels per dim
#define VV (BB * GG * GG * GG)   // 131072 voxel slots

// d_out layout (flat float32, reference return order)
#define OUT_X    0
#define OUT_POS  (VV * FF)                 // 16,777,216
#define OUT_EIDX (OUT_POS + VV * 3)        // 17,170,432
#define OUT_ATTR (OUT_EIDX + 2 * EE)       // 25,170,432
#define OUT_MASK (OUT_ATTR + 3 * EE)       // 37,170,432
// total = 41,170,432 floats

// ---------------------------------------------------------------------------
// Per-node: compute voxel id, scatter count/pos-sum (thread 0), scatter-max
// features via order-preserving uint atomicMax into the pooled_x out region.
// Grid: NN blocks x 128 threads (one feature per thread).
// ---------------------------------------------------------------------------
__global__ __launch_bounds__(128) void node_kernel(
    const float* __restrict__ x, const float* __restrict__ pos,
    const int* __restrict__ batch, int* __restrict__ vid,
    unsigned int* __restrict__ cnt, float* __restrict__ pos_sum,
    unsigned int* __restrict__ xmax)
{
    int n = blockIdx.x;
    __shared__ int s_vid;
    if (threadIdx.x == 0) {
        float px = pos[3 * n + 0], py = pos[3 * n + 1], pz = pos[3 * n + 2];
        int vx = min(max((int)floorf(px * 0.125f), 0), GG - 1);
        int vy = min(max((int)floorf(py * 0.125f), 0), GG - 1);
        int vz = min(max((int)floorf(pz * 0.125f), 0), GG - 1);
        int v = batch[n] * (GG * GG * GG) + vx * (GG * GG) + vy * GG + vz;
        s_vid = v;
        vid[n] = v;
        atomicAdd(&cnt[v], 1u);
        atomicAdd(&pos_sum[3 * v + 0], px);
        atomicAdd(&pos_sum[3 * v + 1], py);
        atomicAdd(&pos_sum[3 * v + 2], pz);
    }
    __syncthreads();
    int v = s_vid;
    float f = x[(size_t)n * FF + threadIdx.x];
    unsigned int u = __float_as_uint(f);
    // order-preserving monotone map: f0 < f1  <=>  key(f0) < key(f1) (unsigned)
    unsigned int key = (u & 0x80000000u) ? ~u : (u | 0x80000000u);
    atomicMax(&xmax[(size_t)v * FF + threadIdx.x], key);
}

// ---------------------------------------------------------------------------
// Decode pooled_x keys in place; zero unoccupied voxels. VV*FF threads.
// ---------------------------------------------------------------------------
__global__ __launch_bounds__(256) void fix_x_kernel(
    float* __restrict__ out_x, const unsigned int* __restrict__ cnt)
{
    int i = blockIdx.x * 256 + threadIdx.x;     // < VV*FF = 16,777,216
    unsigned int key = __float_as_uint(out_x[i]);
    float f = 0.0f;
    if (cnt[i >> 7] != 0u) {
        unsigned int u = (key & 0x80000000u) ? (key ^ 0x80000000u) : ~key;
        f = __uint_as_float(u);
    }
    out_x[i] = f;
}

// ---------------------------------------------------------------------------
// pooled_pos = pos_sum / max(count, 1). VV threads.
// ---------------------------------------------------------------------------
__global__ __launch_bounds__(256) void fix_pos_kernel(
    float* __restrict__ out_pos, const float* __restrict__ pos_sum,
    const unsigned int* __restrict__ cnt)
{
    int v = blockIdx.x * 256 + threadIdx.x;
    float inv = 1.0f / fmaxf((float)cnt[v], 1.0f);
    out_pos[3 * v + 0] = pos_sum[3 * v + 0] * inv;
    out_pos[3 * v + 1] = pos_sum[3 * v + 1] * inv;
    out_pos[3 * v + 2] = pos_sum[3 * v + 2] * inv;
}

// ---------------------------------------------------------------------------
// Per-edge: remap endpoints to voxel ids, self-loop mask, Cartesian attr.
// edge_attr = (pos[dst]-pos[src]) / (2*8.0) + 0.5, zeroed on self-loops.
// ---------------------------------------------------------------------------
__global__ __launch_bounds__(256) void edge_kernel(
    const int* __restrict__ eidx, const int* __restrict__ vid,
    const float* __restrict__ pooled_pos, float* __restrict__ out)
{
    int e = blockIdx.x * 256 + threadIdx.x;
    if (e >= EE) return;
    int sv = vid[eidx[e]];
    int dv = vid[eidx[EE + e]];
    bool m = (sv != dv);
    out[OUT_EIDX + e] = (float)sv;
    out[OUT_EIDX + EE + e] = (float)dv;
    float ax = 0.0f, ay = 0.0f, az = 0.0f;
    if (m) {
        ax = (pooled_pos[3 * dv + 0] - pooled_pos[3 * sv + 0]) * 0.0625f + 0.5f;
        ay = (pooled_pos[3 * dv + 1] - pooled_pos[3 * sv + 1]) * 0.0625f + 0.5f;
        az = (pooled_pos[3 * dv + 2] - pooled_pos[3 * sv + 2]) * 0.0625f + 0.5f;
    }
    out[OUT_ATTR + 3 * e + 0] = ax;
    out[OUT_ATTR + 3 * e + 1] = ay;
    out[OUT_ATTR + 3 * e + 2] = az;
    out[OUT_MASK + e] = m ? 1.0f : 0.0f;
}

extern "C" void kernel_launch(void* const* d_in, const int* in_sizes, int n_in,
                              void* d_out, int out_size, void* d_ws, size_t ws_size,
                              hipStream_t stream)
{
    const float* x     = (const float*)d_in[0];
    const float* pos   = (const float*)d_in[1];
    const int*   batch = (const int*)d_in[2];
    const int*   eidx  = (const int*)d_in[3];
    float* out = (float*)d_out;

    // workspace: [count: VV u32][pos_sum: 3*VV f32][vid: NN i32]  ~4.1 MB
    unsigned int* cnt     = (unsigned int*)d_ws;
    float*        pos_sum = (float*)((char*)d_ws + (size_t)VV * 4);
    int*          vid     = (int*)((char*)d_ws + (size_t)VV * 16);

    // zero count + pos_sum (ws is poisoned 0xAA before every call), and the
    // pooled_x region (0x00000000 is the minimal order-preserving key).
    hipMemsetAsync(d_ws, 0, (size_t)VV * 16, stream);
    hipMemsetAsync(out + OUT_X, 0, (size_t)VV * FF * 4, stream);

    node_kernel<<<NN, 128, 0, stream>>>(x, pos, batch, vid, cnt, pos_sum,
                                        (unsigned int*)(out + OUT_X));
    fix_x_kernel<<<(VV * FF) / 256, 256, 0, stream>>>(out + OUT_X, cnt);
    fix_pos_kernel<<<VV / 256, 256, 0, stream>>>(out + OUT_POS, pos_sum, cnt);
    edge_kernel<<<(EE + 255) / 256, 256, 0, stream>>>(eidx, vid, out + OUT_POS, out);
}

// Round 2
// 671.022 us; speedup vs baseline: 1.1460x; 1.1460x over previous
//
#include <hip/hip_runtime.h>

// Problem constants (match reference)
#define NN 500000          // nodes
#define FF 128             // feature dim
#define EE 4000000         // edges
#define BB 4               // graphs
#define GG 32              // voxels per dim
#define VV (BB * GG * GG * GG)   // 131072 voxel slots

// d_out layout (flat float32, reference return order)
#define OUT_X    0
#define OUT_POS  (VV * FF)                 // 16,777,216
#define OUT_EIDX (OUT_POS + VV * 3)        // 17,170,432
#define OUT_ATTR (OUT_EIDX + 2 * EE)       // 25,170,432
#define OUT_MASK (OUT_ATTR + 3 * EE)       // 37,170,432

// ---------------------------------------------------------------------------
// Per-node: voxel id, histogram, pos sums. 2.5M atomics on a 2 MB L2-resident
// region — cheap (vs 64M fabric atomics in the previous version).
// ---------------------------------------------------------------------------
__global__ __launch_bounds__(256) void vid_kernel(
    const float* __restrict__ pos, const int* __restrict__ batch,
    int* __restrict__ vid, unsigned int* __restrict__ cnt,
    float* __restrict__ pos_sum)
{
    int n = blockIdx.x * 256 + threadIdx.x;
    if (n >= NN) return;
    float px = pos[3 * n + 0], py = pos[3 * n + 1], pz = pos[3 * n + 2];
    int vx = min(max((int)floorf(px * 0.125f), 0), GG - 1);
    int vy = min(max((int)floorf(py * 0.125f), 0), GG - 1);
    int vz = min(max((int)floorf(pz * 0.125f), 0), GG - 1);
    int v = batch[n] * (GG * GG * GG) + vx * (GG * GG) + vy * GG + vz;
    vid[n] = v;
    atomicAdd(&cnt[v], 1u);
    atomicAdd(&pos_sum[3 * v + 0], px);
    atomicAdd(&pos_sum[3 * v + 1], py);
    atomicAdd(&pos_sum[3 * v + 2], pz);
}

// ---------------------------------------------------------------------------
// 3-pass exclusive scan over cnt[VV] -> offs[VV].
// ---------------------------------------------------------------------------
__global__ __launch_bounds__(256) void scan_local_kernel(
    const unsigned int* __restrict__ cnt, unsigned int* __restrict__ offs,
    unsigned int* __restrict__ bsum)
{
    __shared__ unsigned int s[256];
    int i = blockIdx.x * 256 + threadIdx.x;
    unsigned int val = cnt[i];
    s[threadIdx.x] = val;
    __syncthreads();
    for (int d = 1; d < 256; d <<= 1) {
        unsigned int t = (threadIdx.x >= d) ? s[threadIdx.x - d] : 0u;
        __syncthreads();
        s[threadIdx.x] += t;
        __syncthreads();
    }
    offs[i] = s[threadIdx.x] - val;              // exclusive
    if (threadIdx.x == 255) bsum[blockIdx.x] = s[255];
}

__global__ __launch_bounds__(512) void scan_bsum_kernel(unsigned int* __restrict__ bsum)
{
    __shared__ unsigned int s[512];
    unsigned int val = bsum[threadIdx.x];
    s[threadIdx.x] = val;
    __syncthreads();
    for (int d = 1; d < 512; d <<= 1) {
        unsigned int t = (threadIdx.x >= d) ? s[threadIdx.x - d] : 0u;
        __syncthreads();
        s[threadIdx.x] += t;
        __syncthreads();
    }
    bsum[threadIdx.x] = s[threadIdx.x] - val;    // exclusive
}

__global__ __launch_bounds__(256) void scan_add_kernel(
    unsigned int* __restrict__ offs, const unsigned int* __restrict__ bsum,
    unsigned int* __restrict__ cursor)
{
    int i = blockIdx.x * 256 + threadIdx.x;
    unsigned int o = offs[i] + bsum[blockIdx.x];
    offs[i] = o;
    cursor[i] = o;
}

// ---------------------------------------------------------------------------
// Scatter node ids into CSR order (counting sort placement).
// ---------------------------------------------------------------------------
__global__ __launch_bounds__(256) void scatter_kernel(
    const int* __restrict__ vid, unsigned int* __restrict__ cursor,
    unsigned int* __restrict__ order)
{
    int n = blockIdx.x * 256 + threadIdx.x;
    if (n >= NN) return;
    unsigned int p = atomicAdd(&cursor[vid[n]], 1u);
    order[p] = n;
}

// ---------------------------------------------------------------------------
// One wave per voxel: gather its node rows (float2/lane = 512 B/wave,
// coalesced) and reduce with register fmaxf. Writes every voxel exactly once
// (0 for empty) — no memset, no fixup pass, no atomics.
// ---------------------------------------------------------------------------
__global__ __launch_bounds__(256) void pool_kernel(
    const float* __restrict__ x, const unsigned int* __restrict__ order,
    const unsigned int* __restrict__ offs, const unsigned int* __restrict__ cnt,
    float* __restrict__ out_x)
{
    int w = threadIdx.x >> 6;          // wave index in block
    int lane = threadIdx.x & 63;
    int v = blockIdx.x * 4 + w;
    unsigned int start = offs[v];
    unsigned int c = cnt[v];
    float2 m = make_float2(0.0f, 0.0f);
    if (c) {
        m.x = -INFINITY; m.y = -INFINITY;
        for (unsigned int k = 0; k < c; ++k) {
            unsigned int node = order[start + k];
            float2 val = ((const float2*)(x + (size_t)node * FF))[lane];
            m.x = fmaxf(m.x, val.x);
            m.y = fmaxf(m.y, val.y);
        }
    }
    ((float2*)(out_x + (size_t)v * FF))[lane] = m;
}

// ---------------------------------------------------------------------------
// pooled_pos = pos_sum / max(count, 1).
// ---------------------------------------------------------------------------
__global__ __launch_bounds__(256) void fix_pos_kernel(
    float* __restrict__ out_pos, const float* __restrict__ pos_sum,
    const unsigned int* __restrict__ cnt)
{
    int v = blockIdx.x * 256 + threadIdx.x;
    float inv = 1.0f / fmaxf((float)cnt[v], 1.0f);
    out_pos[3 * v + 0] = pos_sum[3 * v + 0] * inv;
    out_pos[3 * v + 1] = pos_sum[3 * v + 1] * inv;
    out_pos[3 * v + 2] = pos_sum[3 * v + 2] * inv;
}

// ---------------------------------------------------------------------------
// Per-edge: remap endpoints, self-loop mask, Cartesian attr.
// ---------------------------------------------------------------------------
__global__ __launch_bounds__(256) void edge_kernel(
    const int* __restrict__ eidx, const int* __restrict__ vid,
    const float* __restrict__ pooled_pos, float* __restrict__ out)
{
    int e = blockIdx.x * 256 + threadIdx.x;
    if (e >= EE) return;
    int sv = vid[eidx[e]];
    int dv = vid[eidx[EE + e]];
    bool m = (sv != dv);
    out[OUT_EIDX + e] = (float)sv;
    out[OUT_EIDX + EE + e] = (float)dv;
    float ax = 0.0f, ay = 0.0f, az = 0.0f;
    if (m) {
        ax = (pooled_pos[3 * dv + 0] - pooled_pos[3 * sv + 0]) * 0.0625f + 0.5f;
        ay = (pooled_pos[3 * dv + 1] - pooled_pos[3 * sv + 1]) * 0.0625f + 0.5f;
        az = (pooled_pos[3 * dv + 2] - pooled_pos[3 * sv + 2]) * 0.0625f + 0.5f;
    }
    out[OUT_ATTR + 3 * e + 0] = ax;
    out[OUT_ATTR + 3 * e + 1] = ay;
    out[OUT_ATTR + 3 * e + 2] = az;
    out[OUT_MASK + e] = m ? 1.0f : 0.0f;
}

extern "C" void kernel_launch(void* const* d_in, const int* in_sizes, int n_in,
                              void* d_out, int out_size, void* d_ws, size_t ws_size,
                              hipStream_t stream)
{
    const float* x     = (const float*)d_in[0];
    const float* pos   = (const float*)d_in[1];
    const int*   batch = (const int*)d_in[2];
    const int*   eidx  = (const int*)d_in[3];
    float* out = (float*)d_out;

    // workspace layout (bytes):
    char* ws = (char*)d_ws;
    unsigned int* cnt     = (unsigned int*)(ws + 0);               // VV*4   = 524288
    float*        pos_sum = (float*)(ws + 524288);                 // VV*12  -> 2097152
    int*          vid     = (int*)(ws + 2097152);                  // NN*4   -> 4097152
    unsigned int* offs    = (unsigned int*)(ws + 4097152);         // VV*4   -> 4621440
    unsigned int* cursor  = (unsigned int*)(ws + 4621440);         // VV*4   -> 5145728
    unsigned int* bsum    = (unsigned int*)(ws + 5145728);         // 512*4  -> 5147776
    unsigned int* order   = (unsigned int*)(ws + 5147776);         // NN*4   -> 7147776

    // zero cnt + pos_sum only (2 MB)
    hipMemsetAsync(d_ws, 0, 2097152, stream);

    vid_kernel<<<(NN + 255) / 256, 256, 0, stream>>>(pos, batch, vid, cnt, pos_sum);
    scan_local_kernel<<<VV / 256, 256, 0, stream>>>(cnt, offs, bsum);
    scan_bsum_kernel<<<1, 512, 0, stream>>>(bsum);
    scan_add_kernel<<<VV / 256, 256, 0, stream>>>(offs, bsum, cursor);
    scatter_kernel<<<(NN + 255) / 256, 256, 0, stream>>>(vid, cursor, order);
    pool_kernel<<<VV / 4, 256, 0, stream>>>(x, order, offs, cnt, out + OUT_X);
    fix_pos_kernel<<<VV / 256, 256, 0, stream>>>(out + OUT_POS, pos_sum, cnt);
    edge_kernel<<<(EE + 255) / 256, 256, 0, stream>>>(eidx, vid, out + OUT_POS, out);
}